// Round 1
// baseline (2313.084 us; speedup 1.0000x reference)
//
#include <hip/hip_runtime.h>
#include <cstdint>
#include <cstddef>

#define B_    16
#define S_    1024
#define D_    256
#define H_    128
#define ROWS  (B_ * S_)   // 16384
#define G4    (4 * H_)    // 512

__device__ __forceinline__ float sigmoidf_(float x) { return 1.f / (1.f + __expf(-x)); }
__device__ __forceinline__ float tanhf_(float x)    { return 1.f - 2.f / (__expf(2.f * x) + 1.f); }

// ---------------------------------------------------------------------------
// K1: Xpre[row, j] = sum_k X[row,k] * Wxs[k,j] + b_s[j]
//     X [16384,256], Wxs [256,512] -> Xpre [16384,512]
// grid (256, 2), block 256. Tile 64 rows x 256 cols, K-tile 16.
// ---------------------------------------------------------------------------
__global__ __launch_bounds__(256) void k1_xpre(const float* __restrict__ X,
                                               const float* __restrict__ W,
                                               const float* __restrict__ bias,
                                               float* __restrict__ out) {
    __shared__ alignas(16) float As[16][64];
    __shared__ alignas(16) float Bs[16][256];
    const int tid = threadIdx.x;
    const int rowBase = blockIdx.x * 64;
    const int colBase = blockIdx.y * 256;
    const int ty = tid >> 5, tx = tid & 31;
    float acc[8][8] = {};
    for (int kt = 0; kt < D_; kt += 16) {
        {
            int r = tid & 63, k4 = (tid >> 6) << 2;
            float4 a = *(const float4*)(X + (size_t)(rowBase + r) * D_ + kt + k4);
            As[k4 + 0][r] = a.x; As[k4 + 1][r] = a.y; As[k4 + 2][r] = a.z; As[k4 + 3][r] = a.w;
        }
        {
            int kk = tid >> 4, cc = (tid & 15) << 4;
            const float4* src = (const float4*)(W + (size_t)(kt + kk) * G4 + colBase + cc);
            float4* dst = (float4*)&Bs[kk][cc];
            dst[0] = src[0]; dst[1] = src[1]; dst[2] = src[2]; dst[3] = src[3];
        }
        __syncthreads();
        #pragma unroll
        for (int kk = 0; kk < 16; kk++) {
            float a[8], bb[8];
            #pragma unroll
            for (int u = 0; u < 8; u++) a[u] = As[kk][ty * 8 + u];
            #pragma unroll
            for (int u = 0; u < 8; u++) bb[u] = Bs[kk][tx * 8 + u];
            #pragma unroll
            for (int i = 0; i < 8; i++)
                #pragma unroll
                for (int jj = 0; jj < 8; jj++) acc[i][jj] += a[i] * bb[jj];
        }
        __syncthreads();
    }
    #pragma unroll
    for (int i = 0; i < 8; i++) {
        size_t row = rowBase + ty * 8 + i;
        float* o = out + row * G4 + colBase + tx * 8;
        #pragma unroll
        for (int jj = 0; jj < 8; jj++) o[jj] = acc[i][jj] + bias[colBase + tx * 8 + jj];
    }
}

// ---------------------------------------------------------------------------
// K2: sequential sLSTM scan, one block per batch (16 blocks x 512 threads).
// Thread j owns column j of Wh_s in registers (128 fp32).
// Per step: pre_j = xpre + sum_i h[i]*w[i]; gates; state update on j<128;
// LayerNorm; hi written to global.  2 barriers per step.
// ---------------------------------------------------------------------------
__global__ __launch_bounds__(512) void k2_slstm(const float* __restrict__ xpre,
                                                const float* __restrict__ Whs,
                                                const float* __restrict__ lng,
                                                const float* __restrict__ lnb,
                                                float* __restrict__ hiOut) {
    const int b = blockIdx.x;
    const int j = threadIdx.x;
    float w[128];
    #pragma unroll
    for (int i = 0; i < 128; i++) w[i] = Whs[(size_t)i * G4 + j];

    __shared__ float hsm[128];
    __shared__ float act[512];
    __shared__ float red[4];   // [wave0 sum, wave0 sumsq, wave1 sum, wave1 sumsq]

    if (j < 128) hsm[j] = 0.f;
    float c = 0.f, n = 1.f;
    const float gj = (j < 128) ? lng[j] : 0.f;
    const float bj = (j < 128) ? lnb[j] : 0.f;
    const float* xp = xpre + (size_t)b * S_ * G4 + j;
    float xnext = xp[0];
    __syncthreads();

    for (int t = 0; t < S_; t++) {
        float acc = xnext;
        if (t < S_ - 1) xnext = xp[(size_t)(t + 1) * G4];   // prefetch next step
        #pragma unroll
        for (int i = 0; i < 128; i++) acc += hsm[i] * w[i];
        float a;
        if (j < 128)      a = tanhf_(acc);       // z
        else if (j < 256) a = __expf(acc);       // input gate (exp)
        else              a = sigmoidf_(acc);    // forget / output gates
        act[j] = a;
        __syncthreads();   // B1: act complete, matvec reads of hsm complete
        float h = 0.f;
        if (j < 128) {
            float z = act[j], ig = act[j + 128], fg = act[j + 256], og = act[j + 384];
            c = fg * c + ig * z;
            n = fg * n + ig;
            h = og * c / n;
            hsm[j] = h;                       // safe: this-step matvec reads done pre-B1
            float s = h, s2 = h * h;
            #pragma unroll
            for (int off = 32; off; off >>= 1) {
                s  += __shfl_down(s, off);
                s2 += __shfl_down(s2, off);
            }
            if ((j & 63) == 0) { red[(j >> 6) * 2] = s; red[(j >> 6) * 2 + 1] = s2; }
        }
        __syncthreads();   // B2: hsm + red complete
        if (j < 128) {
            float mu   = (red[0] + red[2]) * 0.0078125f;
            float var  = (red[1] + red[3]) * 0.0078125f - mu * mu;
            float rstd = rsqrtf(var + 1e-5f);
            float hv = (h - mu) * rstd * gj + bj;
            hiOut[((size_t)b * S_ + t) * H_ + j] = hv;
        }
    }
}

// ---------------------------------------------------------------------------
// K3a: [16384,128] @ [128,512] -> Q | K*1/sqrt(H) | V | sigmoid(O), stored as
// 4 consecutive [16384,128] arrays at QKVO. grid (256,2), block 256.
// ---------------------------------------------------------------------------
__global__ __launch_bounds__(256) void k3_qkvo(const float* __restrict__ Hi,
                                               const float* __restrict__ Wq,
                                               const float* __restrict__ Wk,
                                               const float* __restrict__ Wv,
                                               const float* __restrict__ Wo,
                                               float* __restrict__ QKVO) {
    __shared__ alignas(16) float As[16][64];
    __shared__ alignas(16) float Bs[16][256];
    const int tid = threadIdx.x;
    const int rowBase = blockIdx.x * 64;
    const int colBase = blockIdx.y * 256;
    const int ty = tid >> 5, tx = tid & 31;
    float acc[8][8] = {};
    for (int kt = 0; kt < H_; kt += 16) {
        {
            int r = tid & 63, k4 = (tid >> 6) << 2;
            float4 a = *(const float4*)(Hi + (size_t)(rowBase + r) * H_ + kt + k4);
            As[k4 + 0][r] = a.x; As[k4 + 1][r] = a.y; As[k4 + 2][r] = a.z; As[k4 + 3][r] = a.w;
        }
        {
            int kk = tid >> 4, cc = (tid & 15) << 4;
            int gcol = colBase + cc;
            const float* Wsel = (gcol < 128) ? Wq : (gcol < 256) ? Wk : (gcol < 384) ? Wv : Wo;
            const float4* src = (const float4*)(Wsel + (size_t)(kt + kk) * H_ + (gcol & 127));
            float4* dst = (float4*)&Bs[kk][cc];
            dst[0] = src[0]; dst[1] = src[1]; dst[2] = src[2]; dst[3] = src[3];
        }
        __syncthreads();
        #pragma unroll
        for (int kk = 0; kk < 16; kk++) {
            float a[8], bb[8];
            #pragma unroll
            for (int u = 0; u < 8; u++) a[u] = As[kk][ty * 8 + u];
            #pragma unroll
            for (int u = 0; u < 8; u++) bb[u] = Bs[kk][tx * 8 + u];
            #pragma unroll
            for (int i = 0; i < 8; i++)
                #pragma unroll
                for (int jj = 0; jj < 8; jj++) acc[i][jj] += a[i] * bb[jj];
        }
        __syncthreads();
    }
    const int gcol = colBase + tx * 8;
    const int sel = gcol >> 7;
    float* outArr = QKVO + (size_t)sel * ROWS * H_ + (gcol & 127);
    const float kscale = 0.08838834764831845f;  // 1/sqrt(128)
    #pragma unroll
    for (int i = 0; i < 8; i++) {
        size_t row = rowBase + ty * 8 + i;
        float* o = outArr + row * H_;
        #pragma unroll
        for (int jj = 0; jj < 8; jj++) {
            float v = acc[i][jj];
            if (sel == 1) v *= kscale;
            if (sel == 3) v = sigmoidf_(v);
            o[jj] = v;
        }
    }
}

// ---------------------------------------------------------------------------
// K3b: im = exp(hi.wi + bi), fm = sigmoid(hi.wf + bf) per row. One wave/row.
// ---------------------------------------------------------------------------
__global__ __launch_bounds__(256) void k3b_if(const float* __restrict__ Hi,
                                              const float* __restrict__ wi,
                                              const float* __restrict__ bi,
                                              const float* __restrict__ wf,
                                              const float* __restrict__ bf,
                                              float* __restrict__ imA,
                                              float* __restrict__ fmA) {
    const int wave = threadIdx.x >> 6;
    const int lane = threadIdx.x & 63;
    const int row = blockIdx.x * 4 + wave;
    const float* h = Hi + (size_t)row * H_;
    float h0 = h[lane], h1 = h[lane + 64];
    float si = h0 * wi[lane] + h1 * wi[lane + 64];
    float sf = h0 * wf[lane] + h1 * wf[lane + 64];
    #pragma unroll
    for (int off = 32; off; off >>= 1) {
        si += __shfl_down(si, off);
        sf += __shfl_down(sf, off);
    }
    if (lane == 0) {
        imA[row] = __expf(si + bi[0]);
        fmA[row] = sigmoidf_(sf + bf[0]);
    }
}

// ---------------------------------------------------------------------------
// K4: mLSTM scan, row-split. 64 blocks = 16 batches x 4 row-quarters.
// Thread (il = tid>>3, jg = tid&7) owns C[rq*32+il][jg*16 .. +16) in regs.
// n_m scan duplicated on threads 0..127 of every block.  2 barriers/step.
// ---------------------------------------------------------------------------
__global__ __launch_bounds__(256) void k4_mlstm(const float* __restrict__ Qp,
                                                const float* __restrict__ Kp,
                                                const float* __restrict__ Vp,
                                                const float* __restrict__ Op,
                                                const float* __restrict__ imA,
                                                const float* __restrict__ fmA,
                                                float* __restrict__ out) {
    const int tid = threadIdx.x;
    const int b  = blockIdx.x >> 2;
    const int rq = blockIdx.x & 3;
    const int il = tid >> 3;
    const int jg = tid & 7;
    const int j0 = jg * 16;
    const int iglob = rq * 32 + il;

    float C[16] = {};
    float nm = 0.f;
    __shared__ float sk[128], sq[128], sv[32], so[32], sscal[2], swsum[4];

    float kr = 0.f, qr = 0.f, vr = 0.f, orr = 0.f, imr = 0.f, fmr = 0.f;
    {
        size_t row = (size_t)b * S_;
        if (tid < 128)      { kr = Kp[row * H_ + tid]; qr = Qp[row * H_ + tid]; }
        else if (tid < 160) vr  = Vp[row * H_ + rq * 32 + (tid - 128)];
        else if (tid < 192) orr = Op[row * H_ + rq * 32 + (tid - 160)];
        else if (tid == 192) { imr = imA[row]; fmr = fmA[row]; }
    }
    for (int t = 0; t < S_; t++) {
        if (tid < 128)      { sk[tid] = kr; sq[tid] = qr; }
        else if (tid < 160) sv[tid - 128] = vr;
        else if (tid < 192) so[tid - 160] = orr;
        else if (tid == 192) { sscal[0] = imr; sscal[1] = fmr; }
        __syncthreads();   // B1: staging done
        if (t < S_ - 1) {  // prefetch next step while computing
            size_t row = (size_t)b * S_ + t + 1;
            if (tid < 128)      { kr = Kp[row * H_ + tid]; qr = Qp[row * H_ + tid]; }
            else if (tid < 160) vr  = Vp[row * H_ + rq * 32 + (tid - 128)];
            else if (tid < 192) orr = Op[row * H_ + rq * 32 + (tid - 160)];
            else if (tid == 192) { imr = imA[row]; fmr = fmA[row]; }
        }
        const float im = sscal[0], fm = sscal[1];
        const float oi = so[il];          // read before B2 (staged this step)
        const float vi = sv[il] * im;
        float numk = 0.f;
        #pragma unroll
        for (int u = 0; u < 16; u++) {
            float kj = sk[j0 + u];
            C[u] = fm * C[u] + vi * kj;
            numk += C[u] * sq[j0 + u];
        }
        numk += __shfl_xor(numk, 1);
        numk += __shfl_xor(numk, 2);
        numk += __shfl_xor(numk, 4);
        float dpart = 0.f;
        if (tid < 128) { nm = fm * nm + im * sk[tid]; dpart = nm * sq[tid]; }
        #pragma unroll
        for (int off = 32; off; off >>= 1) dpart += __shfl_down(dpart, off);
        if ((tid & 63) == 0) swsum[tid >> 6] = dpart;
        __syncthreads();   // B2: swsum done, all LDS reads of this step done
        if (jg == 0) {
            float den = fmaxf(fabsf(swsum[0] + swsum[1] + swsum[2] + swsum[3]), 1.f);
            out[((size_t)b * S_ + t) * H_ + iglob] = oi * numk / den;
        }
        // next-iter staging writes are protected by next B1 (swsum readers
        // must reach it before swsum is rewritten after it).
    }
}

// ---------------------------------------------------------------------------
extern "C" void kernel_launch(void* const* d_in, const int* in_sizes, int n_in,
                              void* d_out, int out_size, void* d_ws, size_t ws_size,
                              hipStream_t stream) {
    const float* x   = (const float*)d_in[0];
    const float* Wxs = (const float*)d_in[1];
    const float* Whs = (const float*)d_in[2];
    const float* bs  = (const float*)d_in[3];
    const float* lng = (const float*)d_in[4];
    const float* lnb = (const float*)d_in[5];
    const float* Wq  = (const float*)d_in[6];
    const float* Wk  = (const float*)d_in[7];
    const float* Wv  = (const float*)d_in[8];
    const float* Wo  = (const float*)d_in[9];
    const float* wi  = (const float*)d_in[10];
    const float* bi  = (const float*)d_in[11];
    const float* wf  = (const float*)d_in[12];
    const float* bf  = (const float*)d_in[13];
    float* out = (float*)d_out;

    float* ws    = (float*)d_ws;
    float* xpre  = ws;                          // [16384,512]; K3 overwrites with QKVO
    float* QKVO  = ws;                          // 4 x [16384,128]
    float* hi    = ws + (size_t)ROWS * G4;      // [16384,128]
    float* imA   = hi + (size_t)ROWS * H_;      // [16384]
    float* fmA   = imA + ROWS;                  // [16384]
    // total: 16384*512 + 16384*128 + 2*16384 floats ~= 42 MB

    float* Qp = QKVO;
    float* Kp = QKVO + (size_t)1 * ROWS * H_;
    float* Vp = QKVO + (size_t)2 * ROWS * H_;
    float* Op = QKVO + (size_t)3 * ROWS * H_;

    k1_xpre<<<dim3(ROWS / 64, 2), 256, 0, stream>>>(x, Wxs, bs, xpre);
    k2_slstm<<<B_, 512, 0, stream>>>(xpre, Whs, lng, lnb, hi);
    k3_qkvo<<<dim3(ROWS / 64, 2), 256, 0, stream>>>(hi, Wq, Wk, Wv, Wo, QKVO);
    k3b_if<<<ROWS / 4, 256, 0, stream>>>(hi, wi, bi, wf, bf, imA, fmA);
    k4_mlstm<<<B_ * 4, 256, 0, stream>>>(Qp, Kp, Vp, Op, imA, fmA, out);
}

// Round 2
// 2295.120 us; speedup vs baseline: 1.0078x; 1.0078x over previous
//
#include <hip/hip_runtime.h>
#include <cstdint>
#include <cstddef>

#define B_    16
#define S_    1024
#define D_    256
#define H_    128
#define ROWS  (B_ * S_)   // 16384
#define G4    (4 * H_)    // 512

typedef _Float16 half2_ __attribute__((ext_vector_type(2)));

#if __has_builtin(__builtin_amdgcn_fdot2)
#define FDOT2(a, b, c) __builtin_amdgcn_fdot2((a), (b), (c), false)
#else
#define FDOT2(a, b, c) ((float)(a).x * (float)(b).x + (float)(a).y * (float)(b).y + (c))
#endif

__device__ __forceinline__ float sigmoidf_(float x) { return 1.f / (1.f + __expf(-x)); }
__device__ __forceinline__ float tanhf_(float x)    { return 1.f - 2.f / (__expf(2.f * x) + 1.f); }

// ---------------------------------------------------------------------------
// K1: Xpre[row, j] = sum_k X[row,k] * Wxs[k,j] + b_s[j]
// ---------------------------------------------------------------------------
__global__ __launch_bounds__(256) void k1_xpre(const float* __restrict__ X,
                                               const float* __restrict__ W,
                                               const float* __restrict__ bias,
                                               float* __restrict__ out) {
    __shared__ alignas(16) float As[16][64];
    __shared__ alignas(16) float Bs[16][256];
    const int tid = threadIdx.x;
    const int rowBase = blockIdx.x * 64;
    const int colBase = blockIdx.y * 256;
    const int ty = tid >> 5, tx = tid & 31;
    float acc[8][8] = {};
    for (int kt = 0; kt < D_; kt += 16) {
        {
            int r = tid & 63, k4 = (tid >> 6) << 2;
            float4 a = *(const float4*)(X + (size_t)(rowBase + r) * D_ + kt + k4);
            As[k4 + 0][r] = a.x; As[k4 + 1][r] = a.y; As[k4 + 2][r] = a.z; As[k4 + 3][r] = a.w;
        }
        {
            int kk = tid >> 4, cc = (tid & 15) << 4;
            const float4* src = (const float4*)(W + (size_t)(kt + kk) * G4 + colBase + cc);
            float4* dst = (float4*)&Bs[kk][cc];
            dst[0] = src[0]; dst[1] = src[1]; dst[2] = src[2]; dst[3] = src[3];
        }
        __syncthreads();
        #pragma unroll
        for (int kk = 0; kk < 16; kk++) {
            float a[8], bb[8];
            #pragma unroll
            for (int u = 0; u < 8; u++) a[u] = As[kk][ty * 8 + u];
            #pragma unroll
            for (int u = 0; u < 8; u++) bb[u] = Bs[kk][tx * 8 + u];
            #pragma unroll
            for (int i = 0; i < 8; i++)
                #pragma unroll
                for (int jj = 0; jj < 8; jj++) acc[i][jj] += a[i] * bb[jj];
        }
        __syncthreads();
    }
    #pragma unroll
    for (int i = 0; i < 8; i++) {
        size_t row = rowBase + ty * 8 + i;
        float* o = out + row * G4 + colBase + tx * 8;
        #pragma unroll
        for (int jj = 0; jj < 8; jj++) o[jj] = acc[i][jj] + bias[colBase + tx * 8 + jj];
    }
}

// ---------------------------------------------------------------------------
// K2: sLSTM scan. 16 blocks (one per batch) x 256 threads (4 waves).
// Thread j owns columns j and j+256 of Wh_s, packed f16 (half2 over k-pairs,
// 128 VGPRs). h broadcast through LDS as half2[64] (256 B/thread/step).
// v_dot2_f32_f16 accumulates in f32; state/LN stay f32.
// ---------------------------------------------------------------------------
__global__ __launch_bounds__(256, 1) void k2_slstm(const float* __restrict__ xpre,
                                                   const float* __restrict__ Whs,
                                                   const float* __restrict__ lng,
                                                   const float* __restrict__ lnb,
                                                   float* __restrict__ hiOut) {
    const int b = blockIdx.x;
    const int j = threadIdx.x;          // 0..255
    const int colA = j;
    const int colB = j + 256;

    half2_ wA[64], wB[64];
    #pragma unroll
    for (int k = 0; k < 64; k++) {
        wA[k] = half2_{(_Float16)Whs[(size_t)(2 * k) * G4 + colA],
                       (_Float16)Whs[(size_t)(2 * k + 1) * G4 + colA]};
        wB[k] = half2_{(_Float16)Whs[(size_t)(2 * k) * G4 + colB],
                       (_Float16)Whs[(size_t)(2 * k + 1) * G4 + colB]};
    }

    __shared__ half2_ hsm[64];          // h(t-1) packed f16
    __shared__ float act[512];
    __shared__ float red[4];
    _Float16* hsmh = (_Float16*)hsm;

    if (j < 64) hsm[j] = half2_{(_Float16)0.f, (_Float16)0.f};
    float c = 0.f, n = 1.f;
    const float gj = (j < 128) ? lng[j] : 0.f;
    const float bj = (j < 128) ? lnb[j] : 0.f;
    const float* xp = xpre + (size_t)b * S_ * G4;
    float xA = xp[colA], xB = xp[colB];
    __syncthreads();

    for (int t = 0; t < S_; t++) {
        float a0 = xA, a1 = 0.f, a2 = 0.f, a3 = 0.f;
        float b0 = xB, b1 = 0.f, b2 = 0.f, b3 = 0.f;
        if (t < S_ - 1) {               // prefetch next step's xpre
            xA = xp[(size_t)(t + 1) * G4 + colA];
            xB = xp[(size_t)(t + 1) * G4 + colB];
        }
        #pragma unroll
        for (int k = 0; k < 64; k += 4) {   // 4 half2 = one ds_read_b128
            half2_ h0 = hsm[k], h1 = hsm[k + 1], h2 = hsm[k + 2], h3 = hsm[k + 3];
            a0 = FDOT2(h0, wA[k],     a0);
            a1 = FDOT2(h1, wA[k + 1], a1);
            a2 = FDOT2(h2, wA[k + 2], a2);
            a3 = FDOT2(h3, wA[k + 3], a3);
            b0 = FDOT2(h0, wB[k],     b0);
            b1 = FDOT2(h1, wB[k + 1], b1);
            b2 = FDOT2(h2, wB[k + 2], b2);
            b3 = FDOT2(h3, wB[k + 3], b3);
        }
        float accA = (a0 + a1) + (a2 + a3);
        float accB = (b0 + b1) + (b2 + b3);
        // colA: z (j<128) or ig (j>=128); colB: fg (j<128) or og (j>=128)
        float rA = (j < 128) ? tanhf_(accA) : __expf(accA);
        float rB = sigmoidf_(accB);
        act[colA] = rA;
        act[colB] = rB;
        __syncthreads();   // B1: act complete, hsm reads of this step done
        float h = 0.f;
        if (j < 128) {
            float z = act[j], ig = act[j + 128], fg = act[j + 256], og = act[j + 384];
            c = fg * c + ig * z;
            n = fg * n + ig;
            h = og * c / n;
            hsmh[j] = (_Float16)h;
            float s = h, s2 = h * h;
            #pragma unroll
            for (int off = 32; off; off >>= 1) {
                s  += __shfl_down(s, off);
                s2 += __shfl_down(s2, off);
            }
            if ((j & 63) == 0) { red[(j >> 6) * 2] = s; red[(j >> 6) * 2 + 1] = s2; }
        }
        __syncthreads();   // B2: hsm + red complete
        if (j < 128) {
            float mu   = (red[0] + red[2]) * 0.0078125f;
            float var  = (red[1] + red[3]) * 0.0078125f - mu * mu;
            float rstd = rsqrtf(var + 1e-5f);
            hiOut[((size_t)b * S_ + t) * H_ + j] = (h - mu) * rstd * gj + bj;
        }
    }
}

// ---------------------------------------------------------------------------
// K3a: [16384,128] @ [128,512] -> Q | K/sqrt(H) | V | sigmoid(O)
// ---------------------------------------------------------------------------
__global__ __launch_bounds__(256) void k3_qkvo(const float* __restrict__ Hi,
                                               const float* __restrict__ Wq,
                                               const float* __restrict__ Wk,
                                               const float* __restrict__ Wv,
                                               const float* __restrict__ Wo,
                                               float* __restrict__ QKVO) {
    __shared__ alignas(16) float As[16][64];
    __shared__ alignas(16) float Bs[16][256];
    const int tid = threadIdx.x;
    const int rowBase = blockIdx.x * 64;
    const int colBase = blockIdx.y * 256;
    const int ty = tid >> 5, tx = tid & 31;
    float acc[8][8] = {};
    for (int kt = 0; kt < H_; kt += 16) {
        {
            int r = tid & 63, k4 = (tid >> 6) << 2;
            float4 a = *(const float4*)(Hi + (size_t)(rowBase + r) * H_ + kt + k4);
            As[k4 + 0][r] = a.x; As[k4 + 1][r] = a.y; As[k4 + 2][r] = a.z; As[k4 + 3][r] = a.w;
        }
        {
            int kk = tid >> 4, cc = (tid & 15) << 4;
            int gcol = colBase + cc;
            const float* Wsel = (gcol < 128) ? Wq : (gcol < 256) ? Wk : (gcol < 384) ? Wv : Wo;
            const float4* src = (const float4*)(Wsel + (size_t)(kt + kk) * H_ + (gcol & 127));
            float4* dst = (float4*)&Bs[kk][cc];
            dst[0] = src[0]; dst[1] = src[1]; dst[2] = src[2]; dst[3] = src[3];
        }
        __syncthreads();
        #pragma unroll
        for (int kk = 0; kk < 16; kk++) {
            float a[8], bb[8];
            #pragma unroll
            for (int u = 0; u < 8; u++) a[u] = As[kk][ty * 8 + u];
            #pragma unroll
            for (int u = 0; u < 8; u++) bb[u] = Bs[kk][tx * 8 + u];
            #pragma unroll
            for (int i = 0; i < 8; i++)
                #pragma unroll
                for (int jj = 0; jj < 8; jj++) acc[i][jj] += a[i] * bb[jj];
        }
        __syncthreads();
    }
    const int gcol = colBase + tx * 8;
    const int sel = gcol >> 7;
    float* outArr = QKVO + (size_t)sel * ROWS * H_ + (gcol & 127);
    const float kscale = 0.08838834764831845f;  // 1/sqrt(128)
    #pragma unroll
    for (int i = 0; i < 8; i++) {
        size_t row = rowBase + ty * 8 + i;
        float* o = outArr + row * H_;
        #pragma unroll
        for (int jj = 0; jj < 8; jj++) {
            float v = acc[i][jj];
            if (sel == 1) v *= kscale;
            if (sel == 3) v = sigmoidf_(v);
            o[jj] = v;
        }
    }
}

// ---------------------------------------------------------------------------
// K3b: im = exp(hi.wi + bi), fm = sigmoid(hi.wf + bf) per row.
// ---------------------------------------------------------------------------
__global__ __launch_bounds__(256) void k3b_if(const float* __restrict__ Hi,
                                              const float* __restrict__ wi,
                                              const float* __restrict__ bi,
                                              const float* __restrict__ wf,
                                              const float* __restrict__ bf,
                                              float* __restrict__ imA,
                                              float* __restrict__ fmA) {
    const int wave = threadIdx.x >> 6;
    const int lane = threadIdx.x & 63;
    const int row = blockIdx.x * 4 + wave;
    const float* h = Hi + (size_t)row * H_;
    float h0 = h[lane], h1 = h[lane + 64];
    float si = h0 * wi[lane] + h1 * wi[lane + 64];
    float sf = h0 * wf[lane] + h1 * wf[lane + 64];
    #pragma unroll
    for (int off = 32; off; off >>= 1) {
        si += __shfl_down(si, off);
        sf += __shfl_down(sf, off);
    }
    if (lane == 0) {
        imA[row] = __expf(si + bi[0]);
        fmA[row] = sigmoidf_(sf + bf[0]);
    }
}

// ---------------------------------------------------------------------------
// K4: mLSTM scan, fully wave-local. 256 blocks = 16 batches x 16 row-groups
// (8 rows each), 64 threads. Lane l owns C[r0..r0+8)[{l, l+64}] in regs.
// n_m duplicated per wave (lane tracks dims l, l+64) -> denominator is an
// in-wave butterfly. Zero barriers, zero LDS; next-step operands prefetched.
// ---------------------------------------------------------------------------
__global__ __launch_bounds__(64) void k4_mlstm(const float* __restrict__ Qp,
                                               const float* __restrict__ Kp,
                                               const float* __restrict__ Vp,
                                               const float* __restrict__ Op,
                                               const float* __restrict__ imA,
                                               const float* __restrict__ fmA,
                                               float* __restrict__ out) {
    const int lane = threadIdx.x;
    const int b  = blockIdx.x >> 4;
    const int rg = blockIdx.x & 15;
    const int r0 = rg * 8;
    const size_t rowbase = (size_t)b * S_;

    float C0[8] = {}, C1[8] = {};
    float nmA = 0.f, nmB = 0.f;

    float kA, kB, qA, qB, im, fm, vv[8], oo[8];
    {
        size_t a = rowbase * H_;
        kA = Kp[a + lane]; kB = Kp[a + lane + 64];
        qA = Qp[a + lane]; qB = Qp[a + lane + 64];
        #pragma unroll
        for (int r = 0; r < 8; r++) { vv[r] = Vp[a + r0 + r]; oo[r] = Op[a + r0 + r]; }
        im = imA[rowbase]; fm = fmA[rowbase];
    }

    for (int t = 0; t < S_; t++) {
        // prefetch next step (clamped at the end; result unused there)
        size_t tn = rowbase + (t + 1 < S_ ? t + 1 : t);
        size_t an = tn * H_;
        float kA2 = Kp[an + lane], kB2 = Kp[an + lane + 64];
        float qA2 = Qp[an + lane], qB2 = Qp[an + lane + 64];
        float vv2[8], oo2[8];
        #pragma unroll
        for (int r = 0; r < 8; r++) { vv2[r] = Vp[an + r0 + r]; oo2[r] = Op[an + r0 + r]; }
        float im2 = imA[tn], fm2 = fmA[tn];

        // denominator (wave-duplicated n_m scan)
        nmA = fm * nmA + im * kA;
        nmB = fm * nmB + im * kB;
        float dp = nmA * qA + nmB * qB;
        #pragma unroll
        for (int off = 32; off; off >>= 1) dp += __shfl_xor(dp, off);
        float rden = 1.0f / fmaxf(fabsf(dp), 1.0f);

        // C update + numerator partials
        float num[8];
        #pragma unroll
        for (int r = 0; r < 8; r++) {
            float vi = vv[r] * im;
            C0[r] = fm * C0[r] + vi * kA;
            C1[r] = fm * C1[r] + vi * kB;
            num[r] = C0[r] * qA + C1[r] * qB;
        }
        #pragma unroll
        for (int off = 32; off; off >>= 1) {
            #pragma unroll
            for (int r = 0; r < 8; r++) num[r] += __shfl_xor(num[r], off);
        }
        // lane r (r<8) stores row r0+r
        float val = num[0] * oo[0];
        #pragma unroll
        for (int r = 1; r < 8; r++) {
            bool p = (lane == r);
            val = p ? num[r] * oo[r] : val;
        }
        if (lane < 8) out[(rowbase + t) * H_ + r0 + lane] = val * rden;

        kA = kA2; kB = kB2; qA = qA2; qB = qB2; im = im2; fm = fm2;
        #pragma unroll
        for (int r = 0; r < 8; r++) { vv[r] = vv2[r]; oo[r] = oo2[r]; }
    }
}

// ---------------------------------------------------------------------------
extern "C" void kernel_launch(void* const* d_in, const int* in_sizes, int n_in,
                              void* d_out, int out_size, void* d_ws, size_t ws_size,
                              hipStream_t stream) {
    const float* x   = (const float*)d_in[0];
    const float* Wxs = (const float*)d_in[1];
    const float* Whs = (const float*)d_in[2];
    const float* bs  = (const float*)d_in[3];
    const float* lng = (const float*)d_in[4];
    const float* lnb = (const float*)d_in[5];
    const float* Wq  = (const float*)d_in[6];
    const float* Wk  = (const float*)d_in[7];
    const float* Wv  = (const float*)d_in[8];
    const float* Wo  = (const float*)d_in[9];
    const float* wi  = (const float*)d_in[10];
    const float* bi  = (const float*)d_in[11];
    const float* wf  = (const float*)d_in[12];
    const float* bf  = (const float*)d_in[13];
    float* out = (float*)d_out;

    float* ws    = (float*)d_ws;
    float* xpre  = ws;                          // [16384,512]; K3 overwrites with QKVO
    float* QKVO  = ws;                          // 4 x [16384,128]
    float* hi    = ws + (size_t)ROWS * G4;      // [16384,128]
    float* imA   = hi + (size_t)ROWS * H_;      // [16384]
    float* fmA   = imA + ROWS;                  // [16384]

    float* Qp = QKVO;
    float* Kp = QKVO + (size_t)1 * ROWS * H_;
    float* Vp = QKVO + (size_t)2 * ROWS * H_;
    float* Op = QKVO + (size_t)3 * ROWS * H_;

    k1_xpre<<<dim3(ROWS / 64, 2), 256, 0, stream>>>(x, Wxs, bs, xpre);
    k2_slstm<<<B_, 256, 0, stream>>>(xpre, Whs, lng, lnb, hi);
    k3_qkvo<<<dim3(ROWS / 64, 2), 256, 0, stream>>>(hi, Wq, Wk, Wv, Wo, QKVO);
    k3b_if<<<ROWS / 4, 256, 0, stream>>>(hi, wi, bi, wf, bf, imA, fmA);
    k4_mlstm<<<B_ * 16, 64, 0, stream>>>(Qp, Kp, Vp, Op, imA, fmA, out);
}

// Round 3
// 1294.030 us; speedup vs baseline: 1.7875x; 1.7736x over previous
//
#include <hip/hip_runtime.h>
#include <cstdint>
#include <cstddef>

#define B_    16
#define S_    1024
#define D_    256
#define H_    128
#define ROWS  (B_ * S_)   // 16384
#define G4    (4 * H_)    // 512
#define L_    64          // mLSTM chunk length
#define NC    16          // chunks per sequence

typedef _Float16 half2_ __attribute__((ext_vector_type(2)));

#if __has_builtin(__builtin_amdgcn_fdot2)
#define FDOT2(a, b, c) __builtin_amdgcn_fdot2((a), (b), (c), false)
#else
#define FDOT2(a, b, c) ((float)(a).x * (float)(b).x + (float)(a).y * (float)(b).y + (c))
#endif

__device__ __forceinline__ float sigmoidf_(float x) { return 1.f / (1.f + __expf(-x)); }
__device__ __forceinline__ float tanhf_(float x)    { return 1.f - 2.f / (__expf(2.f * x) + 1.f); }

// ---------------------------------------------------------------------------
// K1: Xpre[row, j] = sum_k X[row,k] * Wxs[k,j] + b_s[j]
// ---------------------------------------------------------------------------
__global__ __launch_bounds__(256) void k1_xpre(const float* __restrict__ X,
                                               const float* __restrict__ W,
                                               const float* __restrict__ bias,
                                               float* __restrict__ out) {
    __shared__ alignas(16) float As[16][64];
    __shared__ alignas(16) float Bs[16][256];
    const int tid = threadIdx.x;
    const int rowBase = blockIdx.x * 64;
    const int colBase = blockIdx.y * 256;
    const int ty = tid >> 5, tx = tid & 31;
    float acc[8][8] = {};
    for (int kt = 0; kt < D_; kt += 16) {
        {
            int r = tid & 63, k4 = (tid >> 6) << 2;
            float4 a = *(const float4*)(X + (size_t)(rowBase + r) * D_ + kt + k4);
            As[k4 + 0][r] = a.x; As[k4 + 1][r] = a.y; As[k4 + 2][r] = a.z; As[k4 + 3][r] = a.w;
        }
        {
            int kk = tid >> 4, cc = (tid & 15) << 4;
            const float4* src = (const float4*)(W + (size_t)(kt + kk) * G4 + colBase + cc);
            float4* dst = (float4*)&Bs[kk][cc];
            dst[0] = src[0]; dst[1] = src[1]; dst[2] = src[2]; dst[3] = src[3];
        }
        __syncthreads();
        #pragma unroll
        for (int kk = 0; kk < 16; kk++) {
            float a[8], bb[8];
            #pragma unroll
            for (int u = 0; u < 8; u++) a[u] = As[kk][ty * 8 + u];
            #pragma unroll
            for (int u = 0; u < 8; u++) bb[u] = Bs[kk][tx * 8 + u];
            #pragma unroll
            for (int i = 0; i < 8; i++)
                #pragma unroll
                for (int jj = 0; jj < 8; jj++) acc[i][jj] += a[i] * bb[jj];
        }
        __syncthreads();
    }
    #pragma unroll
    for (int i = 0; i < 8; i++) {
        size_t row = rowBase + ty * 8 + i;
        float* o = out + row * G4 + colBase + tx * 8;
        #pragma unroll
        for (int jj = 0; jj < 8; jj++) o[jj] = acc[i][jj] + bias[colBase + tx * 8 + jj];
    }
}

// ---------------------------------------------------------------------------
// K2: sLSTM scan. 16 blocks x 512 threads; thread j owns column j of Wh_s as
// 64 packed half2 VGPRs (no spill). h broadcast via LDS (f16), f32 state/LN.
// ---------------------------------------------------------------------------
__global__ __launch_bounds__(512, 1) void k2_slstm(const float* __restrict__ xpre,
                                                   const float* __restrict__ Whs,
                                                   const float* __restrict__ lng,
                                                   const float* __restrict__ lnb,
                                                   float* __restrict__ hiOut) {
    const int b = blockIdx.x;
    const int j = threadIdx.x;          // 0..511, column j
    half2_ w[64];
    #pragma unroll
    for (int k = 0; k < 64; k++)
        w[k] = half2_{(_Float16)Whs[(size_t)(2 * k) * G4 + j],
                      (_Float16)Whs[(size_t)(2 * k + 1) * G4 + j]};

    __shared__ half2_ hsm[64];
    __shared__ float act[512];
    __shared__ float red[4];
    _Float16* hsmh = (_Float16*)hsm;

    if (j < 64) hsm[j] = half2_{(_Float16)0.f, (_Float16)0.f};
    float c = 0.f, n = 1.f;
    const float gj = (j < 128) ? lng[j] : 0.f;
    const float bj = (j < 128) ? lnb[j] : 0.f;
    const float* xp = xpre + (size_t)b * S_ * G4;
    float xn = xp[j];
    __syncthreads();

    for (int t = 0; t < S_; t++) {
        float a0 = xn, a1 = 0.f, a2 = 0.f, a3 = 0.f;
        if (t < S_ - 1) xn = xp[(size_t)(t + 1) * G4 + j];
        #pragma unroll
        for (int k = 0; k < 64; k += 4) {
            half2_ h0 = hsm[k], h1 = hsm[k + 1], h2 = hsm[k + 2], h3 = hsm[k + 3];
            a0 = FDOT2(h0, w[k],     a0);
            a1 = FDOT2(h1, w[k + 1], a1);
            a2 = FDOT2(h2, w[k + 2], a2);
            a3 = FDOT2(h3, w[k + 3], a3);
        }
        float acc = (a0 + a1) + (a2 + a3);
        float r;
        if (j < 128)      r = tanhf_(acc);
        else if (j < 256) r = __expf(acc);
        else              r = sigmoidf_(acc);
        act[j] = r;
        __syncthreads();   // B1
        float h = 0.f;
        if (j < 128) {
            float z = act[j], ig = act[j + 128], fg = act[j + 256], og = act[j + 384];
            c = fg * c + ig * z;
            n = fg * n + ig;
            h = og * c / n;
            hsmh[j] = (_Float16)h;
            float s = h, s2 = h * h;
            #pragma unroll
            for (int off = 32; off; off >>= 1) {
                s  += __shfl_down(s, off);
                s2 += __shfl_down(s2, off);
            }
            if ((j & 63) == 0) { red[(j >> 6) * 2] = s; red[(j >> 6) * 2 + 1] = s2; }
        }
        __syncthreads();   // B2
        if (j < 128) {
            float mu   = (red[0] + red[2]) * 0.0078125f;
            float var  = (red[1] + red[3]) * 0.0078125f - mu * mu;
            float rstd = rsqrtf(var + 1e-5f);
            hiOut[((size_t)b * S_ + t) * H_ + j] = (h - mu) * rstd * gj + bj;
        }
    }
}

// ---------------------------------------------------------------------------
// K3a: [16384,128] @ [128,512] -> Q | K/sqrt(H) | V | sigmoid(O)
// ---------------------------------------------------------------------------
__global__ __launch_bounds__(256) void k3_qkvo(const float* __restrict__ Hi,
                                               const float* __restrict__ Wq,
                                               const float* __restrict__ Wk,
                                               const float* __restrict__ Wv,
                                               const float* __restrict__ Wo,
                                               float* __restrict__ QKVO) {
    __shared__ alignas(16) float As[16][64];
    __shared__ alignas(16) float Bs[16][256];
    const int tid = threadIdx.x;
    const int rowBase = blockIdx.x * 64;
    const int colBase = blockIdx.y * 256;
    const int ty = tid >> 5, tx = tid & 31;
    float acc[8][8] = {};
    for (int kt = 0; kt < H_; kt += 16) {
        {
            int r = tid & 63, k4 = (tid >> 6) << 2;
            float4 a = *(const float4*)(Hi + (size_t)(rowBase + r) * H_ + kt + k4);
            As[k4 + 0][r] = a.x; As[k4 + 1][r] = a.y; As[k4 + 2][r] = a.z; As[k4 + 3][r] = a.w;
        }
        {
            int kk = tid >> 4, cc = (tid & 15) << 4;
            int gcol = colBase + cc;
            const float* Wsel = (gcol < 128) ? Wq : (gcol < 256) ? Wk : (gcol < 384) ? Wv : Wo;
            const float4* src = (const float4*)(Wsel + (size_t)(kt + kk) * H_ + (gcol & 127));
            float4* dst = (float4*)&Bs[kk][cc];
            dst[0] = src[0]; dst[1] = src[1]; dst[2] = src[2]; dst[3] = src[3];
        }
        __syncthreads();
        #pragma unroll
        for (int kk = 0; kk < 16; kk++) {
            float a[8], bb[8];
            #pragma unroll
            for (int u = 0; u < 8; u++) a[u] = As[kk][ty * 8 + u];
            #pragma unroll
            for (int u = 0; u < 8; u++) bb[u] = Bs[kk][tx * 8 + u];
            #pragma unroll
            for (int i = 0; i < 8; i++)
                #pragma unroll
                for (int jj = 0; jj < 8; jj++) acc[i][jj] += a[i] * bb[jj];
        }
        __syncthreads();
    }
    const int gcol = colBase + tx * 8;
    const int sel = gcol >> 7;
    float* outArr = QKVO + (size_t)sel * ROWS * H_ + (gcol & 127);
    const float kscale = 0.08838834764831845f;  // 1/sqrt(128)
    #pragma unroll
    for (int i = 0; i < 8; i++) {
        size_t row = rowBase + ty * 8 + i;
        float* o = outArr + row * H_;
        #pragma unroll
        for (int jj = 0; jj < 8; jj++) {
            float v = acc[i][jj];
            if (sel == 1) v *= kscale;
            if (sel == 3) v = sigmoidf_(v);
            o[jj] = v;
        }
    }
}

// ---------------------------------------------------------------------------
// K3b: im = exp(hi.wi + bi), fm = sigmoid(hi.wf + bf) per row.
// ---------------------------------------------------------------------------
__global__ __launch_bounds__(256) void k3b_if(const float* __restrict__ Hi,
                                              const float* __restrict__ wi,
                                              const float* __restrict__ bi,
                                              const float* __restrict__ wf,
                                              const float* __restrict__ bf,
                                              float* __restrict__ imA,
                                              float* __restrict__ fmA) {
    const int wave = threadIdx.x >> 6;
    const int lane = threadIdx.x & 63;
    const int row = blockIdx.x * 4 + wave;
    const float* h = Hi + (size_t)row * H_;
    float h0 = h[lane], h1 = h[lane + 64];
    float si = h0 * wi[lane] + h1 * wi[lane + 64];
    float sf = h0 * wf[lane] + h1 * wf[lane + 64];
    #pragma unroll
    for (int off = 32; off; off >>= 1) {
        si += __shfl_down(si, off);
        sf += __shfl_down(sf, off);
    }
    if (lane == 0) {
        imA[row] = __expf(si + bi[0]);
        fmA[row] = sigmoidf_(sf + bf[0]);
    }
}

// ---------------------------------------------------------------------------
// K4a: per-(batch,chunk) summaries. 256 blocks x 256 thr.
//   cum(s) = prefix sum of log fm;  w(s) = exp(cum63-cum(s))*im(s)  (<= im)
//   Ut[j][i] = sum_s w(s) K[s][j] V[s][i]   (128x128, stored row j major)
//   nUt[j]   = sum_s w(s) K[s][j];  P = exp(cum63)
// ---------------------------------------------------------------------------
__global__ __launch_bounds__(256) void k4a_summ(const float* __restrict__ Kp,
                                                const float* __restrict__ Vp,
                                                const float* __restrict__ imA,
                                                const float* __restrict__ fmA,
                                                float* __restrict__ UC,
                                                float* __restrict__ nUn,
                                                float* __restrict__ Pc) {
    const int bc = blockIdx.x;
    const int b = bc >> 4, c = bc & 15;
    const int t0 = c * L_;
    const size_t rowbase = ((size_t)b * S_ + t0) * H_;
    const int tid = threadIdx.x;

    __shared__ alignas(16) float Ks[64][132];
    __shared__ alignas(16) float Vs[64][132];
    __shared__ float wv[64];

    {
        int r0 = tid >> 5, c4 = (tid & 31) * 4;
        #pragma unroll
        for (int rr = 0; rr < 8; rr++) {
            int r = r0 + rr * 8;
            *(float4*)&Ks[r][c4] = *(const float4*)(Kp + rowbase + (size_t)r * H_ + c4);
            *(float4*)&Vs[r][c4] = *(const float4*)(Vp + rowbase + (size_t)r * H_ + c4);
        }
    }
    if (tid < 64) {
        int s = tid;
        float cum = __logf(fmA[(size_t)b * S_ + t0 + s]);
        #pragma unroll
        for (int off = 1; off < 64; off <<= 1) {
            float o = __shfl_up(cum, off);
            if (s >= off) cum += o;
        }
        float cum63 = __shfl(cum, 63);
        wv[s] = __expf(cum63 - cum) * imA[(size_t)b * S_ + t0 + s];
        if (s == 63) Pc[bc] = __expf(cum63);
    }
    __syncthreads();

    const int tj = tid >> 4, ti = tid & 15;
    const int j0 = tj * 8, i0 = ti * 8;
    float acc[8][8] = {};
    for (int s = 0; s < 64; s++) {
        float wsc = wv[s];
        float4 a0 = *(const float4*)&Ks[s][j0];
        float4 a1 = *(const float4*)&Ks[s][j0 + 4];
        float a[8] = {a0.x * wsc, a0.y * wsc, a0.z * wsc, a0.w * wsc,
                      a1.x * wsc, a1.y * wsc, a1.z * wsc, a1.w * wsc};
        float4 b0 = *(const float4*)&Vs[s][i0];
        float4 b1 = *(const float4*)&Vs[s][i0 + 4];
        float bb[8] = {b0.x, b0.y, b0.z, b0.w, b1.x, b1.y, b1.z, b1.w};
        #pragma unroll
        for (int u = 0; u < 8; u++)
            #pragma unroll
            for (int v = 0; v < 8; v++) acc[u][v] += a[u] * bb[v];
    }
    float* Ub = UC + (size_t)bc * (H_ * H_);
    #pragma unroll
    for (int u = 0; u < 8; u++) {
        float* o = Ub + (size_t)(j0 + u) * H_ + i0;
        *(float4*)o       = make_float4(acc[u][0], acc[u][1], acc[u][2], acc[u][3]);
        *(float4*)(o + 4) = make_float4(acc[u][4], acc[u][5], acc[u][6], acc[u][7]);
    }
    if (tid < 128) {
        float a = 0.f;
        for (int s = 0; s < 64; s++) a += wv[s] * Ks[s][tid];
        nUn[(size_t)bc * H_ + tid] = a;
    }
}

// ---------------------------------------------------------------------------
// K4b: inter-chunk scan, in place. After this, UC[b][c] = C state BEFORE
// chunk c (transposed layout [j][i]); nUn[b][c] = n state before chunk c.
// ---------------------------------------------------------------------------
__global__ __launch_bounds__(256) void k4b_scan(float* __restrict__ UC,
                                                float* __restrict__ nUn,
                                                const float* __restrict__ Pc) {
    const int gid = blockIdx.x * 256 + threadIdx.x;
    if (gid < B_ * H_ * H_) {
        int b = gid >> 14, e = gid & (H_ * H_ - 1);
        float tmp = 0.f;
        float* base = UC + (size_t)b * NC * H_ * H_ + e;
        #pragma unroll
        for (int c = 0; c < NC; c++) {
            float u = base[(size_t)c * H_ * H_];
            base[(size_t)c * H_ * H_] = tmp;
            tmp = Pc[b * NC + c] * tmp + u;
        }
    } else if (gid < B_ * H_ * H_ + B_ * H_) {
        int g = gid - B_ * H_ * H_;
        int b = g >> 7, jj = g & 127;
        float tmp = 0.f;
        float* base = nUn + (size_t)b * NC * H_ + jj;
        #pragma unroll
        for (int c = 0; c < NC; c++) {
            float u = base[(size_t)c * H_];
            base[(size_t)c * H_] = tmp;
            tmp = Pc[b * NC + c] * tmp + u;
        }
    }
}

// ---------------------------------------------------------------------------
// K4c: per-(batch,chunk) output. 256 blocks x 256 thr.
//   M(t,s) = (q_t.k_s) exp(cum_t-cum_s) im_s  for s<=t
//   num(t) = M V + ect_t * (Q @ Ct_prev);  den(t) = rowsum(M) + ect_t*(q.n_prev)
//   h = o * num / max(|den|,1)
// ---------------------------------------------------------------------------
__global__ __launch_bounds__(256) void k4c_out(const float* __restrict__ Qp,
                                               const float* __restrict__ Kp,
                                               const float* __restrict__ Vp,
                                               const float* __restrict__ Op,
                                               const float* __restrict__ imA,
                                               const float* __restrict__ fmA,
                                               const float* __restrict__ UC,
                                               const float* __restrict__ nUn,
                                               float* __restrict__ out) {
    const int bc = blockIdx.x;
    const int b = bc >> 4, c = bc & 15;
    const int t0 = c * L_;
    const size_t rowbase = ((size_t)b * S_ + t0) * H_;
    const int tid = threadIdx.x;

    __shared__ alignas(16) float Qs[64][132];
    __shared__ alignas(16) float Ks[64][132];   // later: Ct rows 0..63
    __shared__ alignas(16) float Vs[64][132];   // later: Ct rows 64..127
    __shared__ alignas(16) float Ms[64][68];
    __shared__ float ect[64], cumv[64], imv[64], denv[64], npv[128];

    {
        int r0 = tid >> 5, c4 = (tid & 31) * 4;
        #pragma unroll
        for (int rr = 0; rr < 8; rr++) {
            int r = r0 + rr * 8;
            *(float4*)&Qs[r][c4] = *(const float4*)(Qp + rowbase + (size_t)r * H_ + c4);
            *(float4*)&Ks[r][c4] = *(const float4*)(Kp + rowbase + (size_t)r * H_ + c4);
            *(float4*)&Vs[r][c4] = *(const float4*)(Vp + rowbase + (size_t)r * H_ + c4);
        }
    }
    if (tid < 128) npv[tid] = nUn[(size_t)bc * H_ + tid];
    if (tid < 64) {
        int s = tid;
        float cum = __logf(fmA[(size_t)b * S_ + t0 + s]);
        #pragma unroll
        for (int off = 1; off < 64; off <<= 1) {
            float o = __shfl_up(cum, off);
            if (s >= off) cum += o;
        }
        cumv[s] = cum;
        ect[s] = __expf(cum);
        imv[s] = imA[(size_t)b * S_ + t0 + s];
    }
    __syncthreads();

    // ---- phase 1: masked decayed scores -> Ms
    {
        const int tt = tid >> 4, ts = tid & 15;
        float S4[4][4] = {};
        for (int kk = 0; kk < 128; kk += 4) {
            float4 qa[4], kb[4];
            #pragma unroll
            for (int u = 0; u < 4; u++) {
                qa[u] = *(const float4*)&Qs[tt * 4 + u][kk];
                kb[u] = *(const float4*)&Ks[ts * 4 + u][kk];
            }
            #pragma unroll
            for (int u = 0; u < 4; u++)
                #pragma unroll
                for (int v = 0; v < 4; v++)
                    S4[u][v] += qa[u].x * kb[v].x + qa[u].y * kb[v].y
                              + qa[u].z * kb[v].z + qa[u].w * kb[v].w;
        }
        #pragma unroll
        for (int u = 0; u < 4; u++) {
            int t = tt * 4 + u;
            #pragma unroll
            for (int v = 0; v < 4; v++) {
                int s = ts * 4 + v;
                Ms[t][s] = (s <= t) ? S4[u][v] * __expf(cumv[t] - cumv[s]) * imv[s] : 0.f;
            }
        }
    }
    __syncthreads();

    const int t2 = tid >> 4;       // t-tile: rows t2*4..+4
    const int i2 = tid & 15;       // i-tile: cols i2*8..+8
    const float* Ct = UC + (size_t)bc * (H_ * H_);

    // stage Ct rows 0..63 into Ks space (Ks reads finished at barrier above)
    {
        int r0 = tid >> 5, c4 = (tid & 31) * 4;
        #pragma unroll
        for (int rr = 0; rr < 8; rr++) {
            int r = r0 + rr * 8;
            *(float4*)&Ks[r][c4] = *(const float4*)(Ct + (size_t)r * H_ + c4);
        }
    }

    // ---- phase 2a: intra num = Ms @ Vs
    float numa[4][8] = {};
    for (int s = 0; s < 64; s++) {
        float a[4];
        #pragma unroll
        for (int u = 0; u < 4; u++) a[u] = Ms[t2 * 4 + u][s];
        float4 b0 = *(const float4*)&Vs[s][i2 * 8];
        float4 b1 = *(const float4*)&Vs[s][i2 * 8 + 4];
        float bb[8] = {b0.x, b0.y, b0.z, b0.w, b1.x, b1.y, b1.z, b1.w};
        #pragma unroll
        for (int u = 0; u < 4; u++)
            #pragma unroll
            for (int v = 0; v < 8; v++) numa[u][v] += a[u] * bb[v];
    }
    __syncthreads();   // Vs reads done; Ct-half0 staged & visible

    // stage Ct rows 64..127 into Vs space
    {
        int r0 = tid >> 5, c4 = (tid & 31) * 4;
        #pragma unroll
        for (int rr = 0; rr < 8; rr++) {
            int r = r0 + rr * 8;
            *(float4*)&Vs[r][c4] = *(const float4*)(Ct + (size_t)(64 + r) * H_ + c4);
        }
    }

    // ---- phase 2b part 0: inter += Q[:,0:64] @ Ct[0:64]
    float inter[4][8] = {};
    for (int jj = 0; jj < 64; jj++) {
        float a[4];
        #pragma unroll
        for (int u = 0; u < 4; u++) a[u] = Qs[t2 * 4 + u][jj];
        float4 b0 = *(const float4*)&Ks[jj][i2 * 8];
        float4 b1 = *(const float4*)&Ks[jj][i2 * 8 + 4];
        float bb[8] = {b0.x, b0.y, b0.z, b0.w, b1.x, b1.y, b1.z, b1.w};
        #pragma unroll
        for (int u = 0; u < 4; u++)
            #pragma unroll
            for (int v = 0; v < 8; v++) inter[u][v] += a[u] * bb[v];
    }
    __syncthreads();   // Ct-half1 staged & visible

    // ---- phase 2b part 1: inter += Q[:,64:128] @ Ct[64:128]
    for (int jj = 0; jj < 64; jj++) {
        float a[4];
        #pragma unroll
        for (int u = 0; u < 4; u++) a[u] = Qs[t2 * 4 + u][64 + jj];
        float4 b0 = *(const float4*)&Vs[jj][i2 * 8];
        float4 b1 = *(const float4*)&Vs[jj][i2 * 8 + 4];
        float bb[8] = {b0.x, b0.y, b0.z, b0.w, b1.x, b1.y, b1.z, b1.w};
        #pragma unroll
        for (int u = 0; u < 4; u++)
            #pragma unroll
            for (int v = 0; v < 8; v++) inter[u][v] += a[u] * bb[v];
    }

    // ---- denominator (wave 0)
    if (tid < 64) {
        int t = tid;
        float dsum = 0.f;
        for (int s = 0; s <= t; s++) dsum += Ms[t][s];
        float dq = 0.f;
        for (int jj = 0; jj < 128; jj++) dq += Qs[t][jj] * npv[jj];
        denv[t] = dsum + ect[t] * dq;
    }
    __syncthreads();

    // ---- output
    #pragma unroll
    for (int u = 0; u < 4; u++) {
        int t = t2 * 4 + u;
        float e = ect[t];
        float rd = 1.f / fmaxf(fabsf(denv[t]), 1.f);
        const float* Orow = Op + rowbase + (size_t)t * H_ + i2 * 8;
        float* orow = out + rowbase + (size_t)t * H_ + i2 * 8;
        #pragma unroll
        for (int v = 0; v < 8; v++) {
            float nm = numa[u][v] + e * inter[u][v];
            orow[v] = Orow[v] * nm * rd;
        }
    }
}

// ---------------------------------------------------------------------------
extern "C" void kernel_launch(void* const* d_in, const int* in_sizes, int n_in,
                              void* d_out, int out_size, void* d_ws, size_t ws_size,
                              hipStream_t stream) {
    const float* x   = (const float*)d_in[0];
    const float* Wxs = (const float*)d_in[1];
    const float* Whs = (const float*)d_in[2];
    const float* bs  = (const float*)d_in[3];
    const float* lng = (const float*)d_in[4];
    const float* lnb = (const float*)d_in[5];
    const float* Wq  = (const float*)d_in[6];
    const float* Wk  = (const float*)d_in[7];
    const float* Wv  = (const float*)d_in[8];
    const float* Wo  = (const float*)d_in[9];
    const float* wi  = (const float*)d_in[10];
    const float* bi  = (const float*)d_in[11];
    const float* wf  = (const float*)d_in[12];
    const float* bf  = (const float*)d_in[13];
    float* out = (float*)d_out;

    float* ws   = (float*)d_ws;
    float* xpre = ws;                              // [16384,512]; K3 reuses as QKVO
    float* QKVO = ws;
    float* UC   = ws + (size_t)ROWS * G4;          // 16 MB: [b][c][128][128]
    float* hi   = UC;                              // hi (8 MB) aliases UC; dead before k4a
    float* nUn  = UC + (size_t)B_ * NC * H_ * H_;  // [b][c][128]
    float* Pc   = nUn + (size_t)B_ * NC * H_;      // [b][c]
    float* imA  = Pc + B_ * NC;                    // [16384]
    float* fmA  = imA + ROWS;                      // [16384]
    // total ~50.6 MB

    float* Qp = QKVO;
    float* Kp = QKVO + (size_t)1 * ROWS * H_;
    float* Vp = QKVO + (size_t)2 * ROWS * H_;
    float* Op = QKVO + (size_t)3 * ROWS * H_;

    k1_xpre<<<dim3(ROWS / 64, 2), 256, 0, stream>>>(x, Wxs, bs, xpre);
    k2_slstm<<<B_, 512, 0, stream>>>(xpre, Whs, lng, lnb, hi);
    k3_qkvo<<<dim3(ROWS / 64, 2), 256, 0, stream>>>(hi, Wq, Wk, Wv, Wo, QKVO);
    k3b_if<<<ROWS / 4, 256, 0, stream>>>(hi, wi, bi, wf, bf, imA, fmA);
    k4a_summ<<<B_ * NC, 256, 0, stream>>>(Kp, Vp, imA, fmA, UC, nUn, Pc);
    k4b_scan<<<(B_ * H_ * H_ + B_ * H_ + 255) / 256, 256, 0, stream>>>(UC, nUn, Pc);
    k4c_out<<<B_ * NC, 256, 0, stream>>>(Qp, Kp, Vp, Op, imA, fmA, UC, nUn, out);
}